// Round 7
// baseline (525.653 us; speedup 1.0000x reference)
//
#include <hip/hip_runtime.h>
#include <hip/hip_bf16.h>

#define BT   4096   // B*T
#define CD   1024   // C
#define TD   2048   // T
#define NH   16     // heads
#define DH   64     // head dim

typedef __attribute__((ext_vector_type(8))) short bf16x8;
typedef __attribute__((ext_vector_type(4))) float f32x4;

__device__ inline short f2bf(float f) {
    union { float fv; unsigned u; } x; x.fv = f;
    unsigned r = x.u + 0x7fffu + ((x.u >> 16) & 1u);
    return (short)(r >> 16);
}

__device__ inline void gload_lds16(const short* g, short* lds) {
    __builtin_amdgcn_global_load_lds(
        (const __attribute__((address_space(1))) void*)g,
        (__attribute__((address_space(3))) void*)lds, 16, 0, 0);
}

// ---------------- LayerNorm: one block per row (C=1024), fp32 in, bf16 out ----
__launch_bounds__(256)
__global__ void ln_kernel(const float* __restrict__ x,
                          const float* __restrict__ g,
                          const float* __restrict__ be,
                          short* __restrict__ out) {
    __shared__ float red[2][4];
    const int row = blockIdx.x;
    const float* xr = x + (size_t)row * CD;
    float s = 0.f, ss = 0.f;
    for (int c = threadIdx.x; c < CD; c += 256) {
        float v = xr[c];
        s += v; ss += v * v;
    }
    #pragma unroll
    for (int off = 32; off > 0; off >>= 1) {
        s  += __shfl_down(s,  off, 64);
        ss += __shfl_down(ss, off, 64);
    }
    int wid = threadIdx.x >> 6, lane = threadIdx.x & 63;
    if (lane == 0) { red[0][wid] = s; red[1][wid] = ss; }
    __syncthreads();
    float sum   = red[0][0] + red[0][1] + red[0][2] + red[0][3];
    float sumsq = red[1][0] + red[1][1] + red[1][2] + red[1][3];
    float mu   = sum * (1.f / CD);
    float var  = sumsq * (1.f / CD) - mu * mu;
    float rstd = rsqrtf(var + 1e-5f);
    short* orow = out + (size_t)row * CD;
    for (int c = threadIdx.x; c < CD; c += 256) {
        float v = xr[c];
        orow[c] = f2bf((v - mu) * rstd * g[c] + be[c]);
    }
}

// ------------- Transpose + cast: in (R x Cc) fp32 -> out (Cc x R) bf16 -------
__launch_bounds__(256)
__global__ void transpose_cast(const float* __restrict__ in, short* __restrict__ out,
                               int R, int Cc) {
    __shared__ float t[64][65];
    const int r0 = blockIdx.y * 64, c0 = blockIdx.x * 64;
    const int tid = threadIdx.x;
    #pragma unroll
    for (int i = 0; i < 16; ++i) {
        int e = i * 256 + tid;
        t[e >> 6][e & 63] = in[(size_t)(r0 + (e >> 6)) * Cc + c0 + (e & 63)];
    }
    __syncthreads();
    #pragma unroll
    for (int i = 0; i < 16; ++i) {
        int e = i * 256 + tid;
        out[(size_t)(c0 + (e >> 6)) * R + r0 + (e & 63)] = f2bf(t[e & 63][e >> 6]);
    }
}

// ------------- Fused Wq/Wk/Wv transpose: (H,C,DH) fp32 -> (3,H,DH,C) bf16 ----
__launch_bounds__(256)
__global__ void wqkv_trans(const float* __restrict__ Wq, const float* __restrict__ Wk,
                           const float* __restrict__ Wv, short* __restrict__ out) {
    __shared__ float t[64][65];
    const int which = blockIdx.z >> 4, hz = blockIdx.z & 15;
    const float* in = (which == 0 ? Wq : which == 1 ? Wk : Wv) + (size_t)hz * CD * DH;
    short* o = out + (size_t)which * CD * CD + (size_t)hz * DH * CD;
    const int r0 = blockIdx.y * 64;
    const int tid = threadIdx.x;
    #pragma unroll
    for (int i = 0; i < 16; ++i) {
        int e = i * 256 + tid;
        t[e >> 6][e & 63] = in[(size_t)(r0 + (e >> 6)) * DH + (e & 63)];
    }
    __syncthreads();
    #pragma unroll
    for (int i = 0; i < 16; ++i) {
        int e = i * 256 + tid;
        o[(size_t)(e >> 6) * CD + r0 + (e & 63)] = f2bf(t[e & 63][e >> 6]);
    }
}

// ------------- V transpose: vbf (BT x C bf16) -> vtg[b][h][d][t] bf16 -------
__launch_bounds__(256)
__global__ void vtrans(const short* __restrict__ vin, short* __restrict__ vout) {
    __shared__ short t[64 * 65];
    const int tid = threadIdx.x;
    const int bh = blockIdx.y;
    const int t0 = blockIdx.x * 64;
    const int b = bh >> 4, h = bh & 15;
    const short* src = vin + (size_t)b * TD * CD + (size_t)h * DH;
    short* dst = vout + (size_t)bh * DH * TD;
    #pragma unroll
    for (int i = 0; i < 16; ++i) {
        int e = i * 256 + tid;
        t[(e >> 6) * 65 + (e & 63)] = src[(size_t)(t0 + (e >> 6)) * CD + (e & 63)];
    }
    __syncthreads();
    #pragma unroll
    for (int i = 0; i < 16; ++i) {
        int e = i * 256 + tid;
        int d = e >> 6, tt = e & 63;
        dst[(size_t)d * TD + t0 + tt] = t[tt * 65 + d];
    }
}

// ---------------- MFMA GEMM: C(128 x TN) = A(M x K) . Bt(N x K)^T, bf16 ------
// MODE 1: + bias + fp32 resid -> fp32 out
// MODE 2: + bias, relu -> bf16 out
// MODE 5: QKV merged: N=3072; seg=col>>10 -> outb + seg*BT*CD; seg0 scaled
template <int MODE, int TN>
__launch_bounds__(256)
__global__ void gemm_mfma(const short* __restrict__ A,
                          const short* __restrict__ Bt,
                          const float* __restrict__ bias,
                          const float* __restrict__ resid,
                          float* __restrict__ outf,
                          short* __restrict__ outb,
                          int N, int K) {
    __shared__ short As[128 * 32];
    __shared__ short Bs[TN * 32];
    const int tid = threadIdx.x;
    const int w = tid >> 6, lane = tid & 63;
    const int quad = lane >> 4, l16 = lane & 15;
    const int wr = w >> 1, wc = w & 1;
    const int m0 = blockIdx.y * 128, n0 = blockIdx.x * TN;
    const int NT = TN / 32;

    f32x4 acc[4][NT] = {};

    for (int k0 = 0; k0 < K; k0 += 32) {
        __syncthreads();
        #pragma unroll
        for (int i = 0; i < 2; ++i) {
            int chunk = i * 256 + tid;
            int row = chunk >> 2, kc = chunk & 3;
            gload_lds16(A + (size_t)(m0 + row) * K + k0 + kc * 8,
                        &As[(i * 256 + w * 64) * 8]);
        }
        #pragma unroll
        for (int i = 0; i < TN / 64; ++i) {
            int chunk = i * 256 + tid;
            int row = chunk >> 2, kc = chunk & 3;
            gload_lds16(Bt + (size_t)(n0 + row) * K + k0 + kc * 8,
                        &Bs[(i * 256 + w * 64) * 8]);
        }
        __syncthreads();

        bf16x8 a[4], b[NT];
        #pragma unroll
        for (int mt = 0; mt < 4; ++mt)
            a[mt] = *(const bf16x8*)&As[(wr * 64 + mt * 16 + l16) * 32 + quad * 8];
        #pragma unroll
        for (int nt = 0; nt < NT; ++nt)
            b[nt] = *(const bf16x8*)&Bs[(wc * (TN / 2) + nt * 16 + l16) * 32 + quad * 8];
        #pragma unroll
        for (int mt = 0; mt < 4; ++mt)
            #pragma unroll
            for (int nt = 0; nt < NT; ++nt)
                acc[mt][nt] = __builtin_amdgcn_mfma_f32_16x16x32_bf16(a[mt], b[nt], acc[mt][nt], 0, 0, 0);
    }

    const float qsc = (MODE == 5 && n0 < CD) ? 0.03125f : 1.0f;
    short* ob5 = (MODE == 5) ? outb + (size_t)(n0 >> 10) * BT * CD : nullptr;

    #pragma unroll
    for (int mt = 0; mt < 4; ++mt)
        #pragma unroll
        for (int nt = 0; nt < NT; ++nt)
            #pragma unroll
            for (int reg = 0; reg < 4; ++reg) {
                int row = m0 + wr * 64 + mt * 16 + quad * 4 + reg;
                int col = n0 + wc * (TN / 2) + nt * 16 + l16;
                float v = acc[mt][nt][reg];
                if (MODE == 1) { v += bias[col] + resid[(size_t)row * N + col];
                                 outf[(size_t)row * N + col] = v; }
                if (MODE == 2) { v = fmaxf(v + bias[col], 0.f);
                                 outb[(size_t)row * N + col] = f2bf(v); }
                if (MODE == 5) { ob5[(size_t)row * CD + (col & 1023)] = f2bf(v * qsc); }
            }
}

// ---------------- Flash attention, MFMA bf16, no-max softmax ----------------
// BQ=128, 4 waves x 32 q-rows (2 row-tiles): each Ks/Vt frag read feeds both
// row-tiles (2x read reuse vs R6). Double-buffered staging: global b128 ->
// regs -> compute current tile -> ds_write next buffer -> barrier (1/tile);
// global load latency hidden behind S/PV compute. STR=76: P b16 writes are
// 2-way (free); frag b128 reads balanced 8/bank.
#define BQ   128
#define BK   64
#define STR  76

struct KVRegs { bf16x8 kr[2]; bf16x8 vr[2]; };

__device__ inline void kv_load(const short* __restrict__ k, const short* __restrict__ vt,
                               size_t base, size_t vbase, int kt, int tid, KVRegs& r) {
    #pragma unroll
    for (int i = 0; i < 2; ++i) {
        int chunk = i * 256 + tid;
        r.kr[i] = *(const bf16x8*)&k[base + (size_t)(kt + (chunk >> 3)) * CD + (chunk & 7) * 8];
        r.vr[i] = *(const bf16x8*)&vt[vbase + (size_t)(chunk >> 3) * TD + kt + (chunk & 7) * 8];
    }
}

__device__ inline void kv_write(int tid, const KVRegs& r, short* Ks, short* Vt) {
    #pragma unroll
    for (int i = 0; i < 2; ++i) {
        int chunk = i * 256 + tid;
        *(bf16x8*)&Ks[(chunk >> 3) * STR + (chunk & 7) * 8] = r.kr[i];
        *(bf16x8*)&Vt[(chunk >> 3) * STR + (chunk & 7) * 8] = r.vr[i];
    }
}

__launch_bounds__(256, 2)
__global__ void attn_mfma(const short* __restrict__ q,
                          const short* __restrict__ k,
                          const short* __restrict__ vt,
                          short* __restrict__ o) {
    __shared__ short Ks0[BK * STR], Ks1[BK * STR];
    __shared__ short Vt0[DH * STR], Vt1[DH * STR];
    __shared__ short Pl[4 * 32 * STR];

    const int tid  = threadIdx.x;
    const int w = tid >> 6, lane = tid & 63;
    const int quad = lane >> 4, l16 = lane & 15;
    const int h = blockIdx.y, b = blockIdx.z;
    const int q0 = blockIdx.x * BQ;
    const size_t base  = (size_t)b * TD * CD + (size_t)h * DH;
    const size_t vbase = (size_t)(b * NH + h) * DH * TD;

    // Q A-frags: wave owns 32 q rows = 2 row-tiles (scale pre-folded)
    bf16x8 qf[2][2];
    #pragma unroll
    for (int rt = 0; rt < 2; ++rt) {
        const short* qp = q + base + (size_t)(q0 + w * 32 + rt * 16 + l16) * CD;
        qf[rt][0] = *(const bf16x8*)&qp[quad * 8];
        qf[rt][1] = *(const bf16x8*)&qp[32 + quad * 8];
    }

    float l_p[2][4] = {};
    f32x4 O[2][4] = {};
    short* pw = &Pl[w * 32 * STR];

    // compute one 64-key tile from the given buffers
    auto compute = [&](const short* __restrict__ KsB, const short* __restrict__ VtB) {
        f32x4 S[2][4];
        #pragma unroll
        for (int ct = 0; ct < 4; ++ct) {
            bf16x8 kb0 = *(const bf16x8*)&KsB[(ct * 16 + l16) * STR + quad * 8];
            bf16x8 kb1 = *(const bf16x8*)&KsB[(ct * 16 + l16) * STR + 32 + quad * 8];
            #pragma unroll
            for (int rt = 0; rt < 2; ++rt) {
                f32x4 acc = (f32x4){0.f, 0.f, 0.f, 0.f};
                acc = __builtin_amdgcn_mfma_f32_16x16x32_bf16(qf[rt][0], kb0, acc, 0, 0, 0);
                acc = __builtin_amdgcn_mfma_f32_16x16x32_bf16(qf[rt][1], kb1, acc, 0, 0, 0);
                S[rt][ct] = acc;
            }
        }
        #pragma unroll
        for (int rt = 0; rt < 2; ++rt)
            #pragma unroll
            for (int reg = 0; reg < 4; ++reg)
                #pragma unroll
                for (int ct = 0; ct < 4; ++ct) {
                    float p = __expf(S[rt][ct][reg]);
                    l_p[rt][reg] += p;
                    pw[(rt * 16 + quad * 4 + reg) * STR + ct * 16 + l16] = f2bf(p);
                }
        // same-wave LDS write->read: lgkmcnt-ordered, no barrier needed
        bf16x8 pf[2][2];
        #pragma unroll
        for (int rt = 0; rt < 2; ++rt) {
            pf[rt][0] = *(const bf16x8*)&pw[(rt * 16 + l16) * STR + quad * 8];
            pf[rt][1] = *(const bf16x8*)&pw[(rt * 16 + l16) * STR + 32 + quad * 8];
        }
        #pragma unroll
        for (int dt = 0; dt < 4; ++dt) {
            bf16x8 vf0 = *(const bf16x8*)&VtB[(dt * 16 + l16) * STR + quad * 8];
            bf16x8 vf1 = *(const bf16x8*)&VtB[(dt * 16 + l16) * STR + 32 + quad * 8];
            #pragma unroll
            for (int rt = 0; rt < 2; ++rt) {
                f32x4 acc = O[rt][dt];
                acc = __builtin_amdgcn_mfma_f32_16x16x32_bf16(pf[rt][0], vf0, acc, 0, 0, 0);
                acc = __builtin_amdgcn_mfma_f32_16x16x32_bf16(pf[rt][1], vf1, acc, 0, 0, 0);
                O[rt][dt] = acc;
            }
        }
    };

    // prologue: stage tile 0 into buf0
    {
        KVRegs r;
        kv_load(k, vt, base, vbase, 0, tid, r);
        kv_write(tid, r, Ks0, Vt0);
    }

    for (int kt = 0; kt < TD; kt += 2 * BK) {
        __syncthreads();                       // buf0 ready; prior buf1 reads done
        {
            KVRegs r;                          // loads overlap compute(buf0)
            kv_load(k, vt, base, vbase, kt + BK, tid, r);
            compute(Ks0, Vt0);
            kv_write(tid, r, Ks1, Vt1);
        }
        __syncthreads();                       // buf1 ready; buf0 reads done
        if (kt + 2 * BK < TD) {
            KVRegs r;
            kv_load(k, vt, base, vbase, kt + 2 * BK, tid, r);
            compute(Ks1, Vt1);
            kv_write(tid, r, Ks0, Vt0);
        } else {
            compute(Ks1, Vt1);
        }
    }

    #pragma unroll
    for (int rt = 0; rt < 2; ++rt)
        #pragma unroll
        for (int reg = 0; reg < 4; ++reg) {
            float l = l_p[rt][reg];
            #pragma unroll
            for (int msk = 1; msk < 16; msk <<= 1)
                l += __shfl_xor(l, msk, 64);
            float inv = 1.f / l;
            int row = q0 + w * 32 + rt * 16 + quad * 4 + reg;
            short* op = o + base + (size_t)row * CD;
            #pragma unroll
            for (int dt = 0; dt < 4; ++dt)
                op[dt * 16 + l16] = f2bf(O[rt][dt][reg] * inv);
        }
}

extern "C" void kernel_launch(void* const* d_in, const int* in_sizes, int n_in,
                              void* d_out, int out_size, void* d_ws, size_t ws_size,
                              hipStream_t stream) {
    const float* x   = (const float*)d_in[0];
    const float* Wq  = (const float*)d_in[1];
    const float* Wk  = (const float*)d_in[2];
    const float* Wv  = (const float*)d_in[3];
    const float* Wo  = (const float*)d_in[4];
    const float* bo  = (const float*)d_in[5];
    const float* W1  = (const float*)d_in[6];
    const float* b1  = (const float*)d_in[7];
    const float* W2  = (const float*)d_in[8];
    const float* b2  = (const float*)d_in[9];
    const float* g1  = (const float*)d_in[10];
    const float* be1 = (const float*)d_in[11];
    const float* g2  = (const float*)d_in[12];
    const float* be2 = (const float*)d_in[13];
    float* out = (float*)d_out;

    const size_t SZ = (size_t)BT * CD;  // 4M elements
    float* ws  = (float*)d_ws;
    short* qbf = (short*)ws;                       // q|k|v contiguous bf16
    short* kbf = qbf + SZ;
    short* vbf = qbf + 2 * SZ;
    float* x1  = ws + 2 * SZ;                      // [2SZ, 3SZ)
    short* h   = (short*)(ws + 3 * SZ);            // [3SZ, 3.5SZ)
    short* ob  = (short*)(ws + 3 * SZ + SZ / 2);   // [3.5SZ, 4SZ)
    short* wqt = (short*)(ws + 4 * SZ);            // 3xCD*CD + CD*CD
    short* wot = wqt + 3 * CD * CD;
    short* w1t = (short*)(ws + 4 * SZ + SZ / 2);   // [4.5SZ, 5SZ)
    short* w2t = (short*)(ws + 5 * SZ);            // [5SZ, 5.5SZ)
    short* vtg = (short*)(ws + 5 * SZ + SZ / 2);   // [5.5SZ, 6SZ)  V^T global
    short* ff1 = (short*)ws;                       // [0, 2SZ) reuses dead q/k/v

    // 1) h1 = LN(x)  (bf16)
    ln_kernel<<<BT, 256, 0, stream>>>(x, g1, be1, h);

    // 2) weight transposes (bf16 B^T layouts)
    wqkv_trans<<<dim3(1, 16, 48), 256, 0, stream>>>(Wq, Wk, Wv, wqt);
    transpose_cast<<<dim3(16, 16), 256, 0, stream>>>(Wo, wot, CD, CD);
    transpose_cast<<<dim3(64, 16), 256, 0, stream>>>(W1, w1t, CD, 4 * CD);
    transpose_cast<<<dim3(16, 64), 256, 0, stream>>>(W2, w2t, 4 * CD, CD);

    // 3) merged q|k|v = h1 @ [Wq|Wk|Wv]  (bf16; C^-0.5 folded into q segment)
    gemm_mfma<5, 128><<<dim3(24, 32), 256, 0, stream>>>(h, wqt, nullptr, nullptr, nullptr, qbf, 3 * CD, CD);

    // 4) vtg = V^T per (b,h)
    vtrans<<<dim3(TD / 64, 2 * NH), 256, 0, stream>>>(vbf, vtg);

    // 5) attention -> ob (bf16, concat-head layout)
    attn_mfma<<<dim3(TD / BQ, NH, 2), 256, 0, stream>>>(qbf, kbf, vtg, ob);

    // 6) x1 = ob @ Wo + bo + x  (fp32)
    gemm_mfma<1, 64><<<dim3(16, 32), 256, 0, stream>>>(ob, wot, bo, x, x1, nullptr, CD, CD);

    // 7) h2 = LN(x1)  (bf16)
    ln_kernel<<<BT, 256, 0, stream>>>(x1, g2, be2, h);

    // 8) ff1 = relu(h2 @ W1 + b1)  (bf16, N=4096)
    gemm_mfma<2, 128><<<dim3(32, 32), 256, 0, stream>>>(h, w1t, b1, nullptr, nullptr, ff1, 4 * CD, CD);

    // 9) out = ff1 @ W2 + b2 + x1  (fp32, K=4096)
    gemm_mfma<1, 64><<<dim3(16, 32), 256, 0, stream>>>(ff1, w2t, b2, x1, out, nullptr, CD, 4 * CD);
}

// Round 8
// 447.712 us; speedup vs baseline: 1.1741x; 1.1741x over previous
//
#include <hip/hip_runtime.h>
#include <hip/hip_bf16.h>

#define BT   4096   // B*T
#define CD   1024   // C
#define TD   2048   // T
#define NH   16     // heads
#define DH   64     // head dim
#define BB   2      // batch

typedef __attribute__((ext_vector_type(8))) short bf16x8;
typedef __attribute__((ext_vector_type(4))) float f32x4;

__device__ inline short f2bf(float f) {
    union { float fv; unsigned u; } x; x.fv = f;
    unsigned r = x.u + 0x7fffu + ((x.u >> 16) & 1u);
    return (short)(r >> 16);
}
__device__ inline float bf2f(short s) {
    union { unsigned u; float f; } x; x.u = ((unsigned)(unsigned short)s) << 16;
    return x.f;
}
__device__ inline unsigned pk2bf(float a, float b) {
    union { __hip_bfloat162 h; unsigned u; } cv;
    cv.h = __float22bfloat162_rn(float2{a, b});
    return cv.u;
}

__device__ inline void gload_lds16(const short* g, short* lds) {
    __builtin_amdgcn_global_load_lds(
        (const __attribute__((address_space(1))) void*)g,
        (__attribute__((address_space(3))) void*)lds, 16, 0, 0);
}

// ---------------- LayerNorm: one block per row (C=1024), fp32 in, bf16 out ----
__launch_bounds__(256)
__global__ void ln_kernel(const float* __restrict__ x,
                          const float* __restrict__ g,
                          const float* __restrict__ be,
                          short* __restrict__ out) {
    __shared__ float red[2][4];
    const int row = blockIdx.x;
    const float* xr = x + (size_t)row * CD;
    float s = 0.f, ss = 0.f;
    for (int c = threadIdx.x; c < CD; c += 256) {
        float v = xr[c];
        s += v; ss += v * v;
    }
    #pragma unroll
    for (int off = 32; off > 0; off >>= 1) {
        s  += __shfl_down(s,  off, 64);
        ss += __shfl_down(ss, off, 64);
    }
    int wid = threadIdx.x >> 6, lane = threadIdx.x & 63;
    if (lane == 0) { red[0][wid] = s; red[1][wid] = ss; }
    __syncthreads();
    float sum   = red[0][0] + red[0][1] + red[0][2] + red[0][3];
    float sumsq = red[1][0] + red[1][1] + red[1][2] + red[1][3];
    float mu   = sum * (1.f / CD);
    float var  = sumsq * (1.f / CD) - mu * mu;
    float rstd = rsqrtf(var + 1e-5f);
    short* orow = out + (size_t)row * CD;
    for (int c = threadIdx.x; c < CD; c += 256) {
        float v = xr[c];
        orow[c] = f2bf((v - mu) * rstd * g[c] + be[c]);
    }
}

// ------------- Transpose + cast: in (R x Cc) fp32 -> out (Cc x R) bf16 -------
__launch_bounds__(256)
__global__ void transpose_cast(const float* __restrict__ in, short* __restrict__ out,
                               int R, int Cc) {
    __shared__ float t[64][65];
    const int r0 = blockIdx.y * 64, c0 = blockIdx.x * 64;
    const int tid = threadIdx.x;
    #pragma unroll
    for (int i = 0; i < 16; ++i) {
        int e = i * 256 + tid;
        t[e >> 6][e & 63] = in[(size_t)(r0 + (e >> 6)) * Cc + c0 + (e & 63)];
    }
    __syncthreads();
    #pragma unroll
    for (int i = 0; i < 16; ++i) {
        int e = i * 256 + tid;
        out[(size_t)(c0 + (e >> 6)) * R + r0 + (e & 63)] = f2bf(t[e & 63][e >> 6]);
    }
}

// ------------- Fused Wq/Wk/Wv transpose: (H,C,DH) fp32 -> (3,H,DH,C) bf16 ----
__launch_bounds__(256)
__global__ void wqkv_trans(const float* __restrict__ Wq, const float* __restrict__ Wk,
                           const float* __restrict__ Wv, short* __restrict__ out) {
    __shared__ float t[64][65];
    const int which = blockIdx.z >> 4, hz = blockIdx.z & 15;
    const float* in = (which == 0 ? Wq : which == 1 ? Wk : Wv) + (size_t)hz * CD * DH;
    short* o = out + (size_t)which * CD * CD + (size_t)hz * DH * CD;
    const int r0 = blockIdx.y * 64;
    const int tid = threadIdx.x;
    #pragma unroll
    for (int i = 0; i < 16; ++i) {
        int e = i * 256 + tid;
        t[e >> 6][e & 63] = in[(size_t)(r0 + (e >> 6)) * DH + (e & 63)];
    }
    __syncthreads();
    #pragma unroll
    for (int i = 0; i < 16; ++i) {
        int e = i * 256 + tid;
        o[(size_t)(e >> 6) * CD + r0 + (e & 63)] = f2bf(t[e & 63][e >> 6]);
    }
}

// ------------- V transpose: vbf (BT x C bf16) -> vtg[b][h][d][t] bf16 -------
__launch_bounds__(256)
__global__ void vtrans(const short* __restrict__ vin, short* __restrict__ vout) {
    __shared__ short t[64 * 65];
    const int tid = threadIdx.x;
    const int bh = blockIdx.y;
    const int t0 = blockIdx.x * 64;
    const int b = bh >> 4, h = bh & 15;
    const short* src = vin + (size_t)b * TD * CD + (size_t)h * DH;
    short* dst = vout + (size_t)bh * DH * TD;
    #pragma unroll
    for (int i = 0; i < 16; ++i) {
        int e = i * 256 + tid;
        t[(e >> 6) * 65 + (e & 63)] = src[(size_t)(t0 + (e >> 6)) * CD + (e & 63)];
    }
    __syncthreads();
    #pragma unroll
    for (int i = 0; i < 16; ++i) {
        int e = i * 256 + tid;
        int d = e >> 6, tt = e & 63;
        dst[(size_t)d * TD + t0 + tt] = t[tt * 65 + d];
    }
}

// ---------------- MFMA GEMM: C(128 x TN) = A(M x K) . Bt(N x K)^T, bf16 ------
// MODE 1: + bias + fp32 resid -> fp32 out
// MODE 2: + bias, relu -> bf16 out
// MODE 5: QKV merged: N=3072; seg=col>>10 -> outb + seg*BT*CD; seg0 scaled
template <int MODE, int TN>
__launch_bounds__(256)
__global__ void gemm_mfma(const short* __restrict__ A,
                          const short* __restrict__ Bt,
                          const float* __restrict__ bias,
                          const float* __restrict__ resid,
                          float* __restrict__ outf,
                          short* __restrict__ outb,
                          int N, int K) {
    __shared__ short As[128 * 32];
    __shared__ short Bs[TN * 32];
    const int tid = threadIdx.x;
    const int w = tid >> 6, lane = tid & 63;
    const int quad = lane >> 4, l16 = lane & 15;
    const int wr = w >> 1, wc = w & 1;
    const int m0 = blockIdx.y * 128, n0 = blockIdx.x * TN;
    const int NT = TN / 32;

    f32x4 acc[4][NT] = {};

    for (int k0 = 0; k0 < K; k0 += 32) {
        __syncthreads();
        #pragma unroll
        for (int i = 0; i < 2; ++i) {
            int chunk = i * 256 + tid;
            int row = chunk >> 2, kc = chunk & 3;
            gload_lds16(A + (size_t)(m0 + row) * K + k0 + kc * 8,
                        &As[(i * 256 + w * 64) * 8]);
        }
        #pragma unroll
        for (int i = 0; i < TN / 64; ++i) {
            int chunk = i * 256 + tid;
            int row = chunk >> 2, kc = chunk & 3;
            gload_lds16(Bt + (size_t)(n0 + row) * K + k0 + kc * 8,
                        &Bs[(i * 256 + w * 64) * 8]);
        }
        __syncthreads();

        bf16x8 a[4], b[NT];
        #pragma unroll
        for (int mt = 0; mt < 4; ++mt)
            a[mt] = *(const bf16x8*)&As[(wr * 64 + mt * 16 + l16) * 32 + quad * 8];
        #pragma unroll
        for (int nt = 0; nt < NT; ++nt)
            b[nt] = *(const bf16x8*)&Bs[(wc * (TN / 2) + nt * 16 + l16) * 32 + quad * 8];
        #pragma unroll
        for (int mt = 0; mt < 4; ++mt)
            #pragma unroll
            for (int nt = 0; nt < NT; ++nt)
                acc[mt][nt] = __builtin_amdgcn_mfma_f32_16x16x32_bf16(a[mt], b[nt], acc[mt][nt], 0, 0, 0);
    }

    const float qsc = (MODE == 5 && n0 < CD) ? 0.03125f : 1.0f;
    short* ob5 = (MODE == 5) ? outb + (size_t)(n0 >> 10) * BT * CD : nullptr;

    #pragma unroll
    for (int mt = 0; mt < 4; ++mt)
        #pragma unroll
        for (int nt = 0; nt < NT; ++nt)
            #pragma unroll
            for (int reg = 0; reg < 4; ++reg) {
                int row = m0 + wr * 64 + mt * 16 + quad * 4 + reg;
                int col = n0 + wc * (TN / 2) + nt * 16 + l16;
                float v = acc[mt][nt][reg];
                if (MODE == 1) { v += bias[col] + resid[(size_t)row * N + col];
                                 outf[(size_t)row * N + col] = v; }
                if (MODE == 2) { v = fmaxf(v + bias[col], 0.f);
                                 outb[(size_t)row * N + col] = f2bf(v); }
                if (MODE == 5) { ob5[(size_t)row * CD + (col & 1023)] = f2bf(v * qsc); }
            }
}

// ---------------- Flash attention, split-K, MFMA bf16, no-max softmax --------
// R5 single-buffer structure (proven fastest) + conflict-free V staging from
// pre-transposed vtg + STR=76 (P b16 writes 2-way free, frag reads balanced).
// Split-K: blockIdx.z = b*2+split; each block does TD/2 keys; partial
// (unnormalized O bf16, l fp32) merged by attn_combine (no-max softmax =>
// partials combine as (O0+O1)/(l0+l1)). Grid 1024 -> 4 blocks/CU, 16 waves.
#define BQ   128
#define BK   64
#define STR  76

__launch_bounds__(256)
__global__ void attn_mfma(const short* __restrict__ q,
                          const short* __restrict__ k,
                          const short* __restrict__ vt,
                          short* __restrict__ opart,
                          float* __restrict__ lpart) {
    __shared__ short Ks[BK * STR];
    __shared__ short Vt[DH * STR];
    __shared__ short Pl[BQ * STR];

    const int tid  = threadIdx.x;
    const int w = tid >> 6, lane = tid & 63;
    const int quad = lane >> 4, l16 = lane & 15;
    const int h = blockIdx.y;
    const int b = blockIdx.z >> 1, split = blockIdx.z & 1;
    const int q0 = blockIdx.x * BQ;
    const size_t base  = (size_t)b * TD * CD + (size_t)h * DH;
    const size_t vbase = (size_t)(b * NH + h) * DH * TD;

    // Q A-frags: wave owns 32 q rows = 2 row-tiles (scale pre-folded)
    bf16x8 qf[2][2];
    #pragma unroll
    for (int rt = 0; rt < 2; ++rt) {
        const short* qp = q + base + (size_t)(q0 + w * 32 + rt * 16 + l16) * CD;
        qf[rt][0] = *(const bf16x8*)&qp[quad * 8];
        qf[rt][1] = *(const bf16x8*)&qp[32 + quad * 8];
    }

    float l_p[2][4] = {};
    f32x4 O[2][4] = {};
    short* pw = &Pl[w * 32 * STR];

    const int kbeg = split * (TD / 2), kend = kbeg + TD / 2;
    for (int kt = kbeg; kt < kend; kt += BK) {
        __syncthreads();
        #pragma unroll
        for (int i = 0; i < 2; ++i) {
            int chunk = i * 256 + tid;
            int r8 = chunk >> 3, c8 = (chunk & 7) * 8;
            *(bf16x8*)&Ks[r8 * STR + c8] =
                *(const bf16x8*)&k[base + (size_t)(kt + r8) * CD + c8];
            *(bf16x8*)&Vt[r8 * STR + c8] =
                *(const bf16x8*)&vt[vbase + (size_t)r8 * TD + kt + c8];
        }
        __syncthreads();

        // S = Q.K^T  (C-layout: row q = quad*4+reg, col key = ct*16+l16)
        f32x4 S[2][4];
        #pragma unroll
        for (int ct = 0; ct < 4; ++ct) {
            bf16x8 kb0 = *(const bf16x8*)&Ks[(ct * 16 + l16) * STR + quad * 8];
            bf16x8 kb1 = *(const bf16x8*)&Ks[(ct * 16 + l16) * STR + 32 + quad * 8];
            #pragma unroll
            for (int rt = 0; rt < 2; ++rt) {
                f32x4 acc = (f32x4){0.f, 0.f, 0.f, 0.f};
                acc = __builtin_amdgcn_mfma_f32_16x16x32_bf16(qf[rt][0], kb0, acc, 0, 0, 0);
                acc = __builtin_amdgcn_mfma_f32_16x16x32_bf16(qf[rt][1], kb1, acc, 0, 0, 0);
                S[rt][ct] = acc;
            }
        }

        // P = exp(S) -> per-wave LDS (C-layout -> A-layout); packed bf16 cvt
        #pragma unroll
        for (int rt = 0; rt < 2; ++rt)
            #pragma unroll
            for (int reg = 0; reg < 4; ++reg) {
                float p0 = __expf(S[rt][0][reg]), p1 = __expf(S[rt][1][reg]);
                float p2 = __expf(S[rt][2][reg]), p3 = __expf(S[rt][3][reg]);
                l_p[rt][reg] += (p0 + p1) + (p2 + p3);
                unsigned u01 = pk2bf(p0, p1), u23 = pk2bf(p2, p3);
                short* pr = &pw[(rt * 16 + quad * 4 + reg) * STR + l16];
                pr[0]  = (short)u01; pr[16] = (short)(u01 >> 16);
                pr[32] = (short)u23; pr[48] = (short)(u23 >> 16);
            }
        // same-wave LDS write->read: lgkmcnt-ordered, no barrier needed

        bf16x8 pf[2][2];
        #pragma unroll
        for (int rt = 0; rt < 2; ++rt) {
            pf[rt][0] = *(const bf16x8*)&pw[(rt * 16 + l16) * STR + quad * 8];
            pf[rt][1] = *(const bf16x8*)&pw[(rt * 16 + l16) * STR + 32 + quad * 8];
        }
        #pragma unroll
        for (int dt = 0; dt < 4; ++dt) {
            bf16x8 vf0 = *(const bf16x8*)&Vt[(dt * 16 + l16) * STR + quad * 8];
            bf16x8 vf1 = *(const bf16x8*)&Vt[(dt * 16 + l16) * STR + 32 + quad * 8];
            #pragma unroll
            for (int rt = 0; rt < 2; ++rt) {
                f32x4 acc = O[rt][dt];
                acc = __builtin_amdgcn_mfma_f32_16x16x32_bf16(pf[rt][0], vf0, acc, 0, 0, 0);
                acc = __builtin_amdgcn_mfma_f32_16x16x32_bf16(pf[rt][1], vf1, acc, 0, 0, 0);
                O[rt][dt] = acc;
            }
        }
    }

    // epilogue: unnormalized O (bf16) + l (fp32) per split
    short* osp = opart + (size_t)split * BT * CD;
    float* lsp = lpart + (size_t)split * BB * NH * TD + (size_t)(b * NH + h) * TD;
    #pragma unroll
    for (int rt = 0; rt < 2; ++rt)
        #pragma unroll
        for (int reg = 0; reg < 4; ++reg) {
            float l = l_p[rt][reg];
            #pragma unroll
            for (int msk = 1; msk < 16; msk <<= 1)
                l += __shfl_xor(l, msk, 64);
            int row = q0 + w * 32 + rt * 16 + quad * 4 + reg;
            if (l16 == 0) lsp[row] = l;
            short* op = osp + base + (size_t)row * CD;
            #pragma unroll
            for (int dt = 0; dt < 4; ++dt)
                op[dt * 16 + l16] = f2bf(O[rt][dt][reg]);
        }
}

// ---------------- Combine split-K partials: ob = (O0+O1)/(l0+l1), bf16 -------
__launch_bounds__(256)
__global__ void attn_combine(const short* __restrict__ opart,
                             const float* __restrict__ lpart,
                             short* __restrict__ ob) {
    const size_t idx = ((size_t)blockIdx.x * 256 + threadIdx.x) * 8;
    const int row = (int)(idx >> 10);        // / CD
    const int col = (int)(idx & 1023);
    const int b = row >> 11, qq = row & (TD - 1), hh = col >> 6;
    const size_t lbase = (size_t)(b * NH + hh) * TD + qq;
    const float l0 = lpart[lbase];
    const float l1 = lpart[(size_t)BB * NH * TD + lbase];
    const float inv = 1.f / (l0 + l1);
    bf16x8 a = *(const bf16x8*)&opart[idx];
    bf16x8 c = *(const bf16x8*)&opart[(size_t)BT * CD + idx];
    bf16x8 r;
    #pragma unroll
    for (int j = 0; j < 8; ++j)
        r[j] = f2bf((bf2f(a[j]) + bf2f(c[j])) * inv);
    *(bf16x8*)&ob[idx] = r;
}

extern "C" void kernel_launch(void* const* d_in, const int* in_sizes, int n_in,
                              void* d_out, int out_size, void* d_ws, size_t ws_size,
                              hipStream_t stream) {
    const float* x   = (const float*)d_in[0];
    const float* Wq  = (const float*)d_in[1];
    const float* Wk  = (const float*)d_in[2];
    const float* Wv  = (const float*)d_in[3];
    const float* Wo  = (const float*)d_in[4];
    const float* bo  = (const float*)d_in[5];
    const float* W1  = (const float*)d_in[6];
    const float* b1  = (const float*)d_in[7];
    const float* W2  = (const float*)d_in[8];
    const float* b2  = (const float*)d_in[9];
    const float* g1  = (const float*)d_in[10];
    const float* be1 = (const float*)d_in[11];
    const float* g2  = (const float*)d_in[12];
    const float* be2 = (const float*)d_in[13];
    float* out = (float*)d_out;

    const size_t SZ = (size_t)BT * CD;  // 4M elements
    float* ws  = (float*)d_ws;
    short* qbf = (short*)ws;                       // [0,1.5SZ): q|k|v bf16
    short* kbf = qbf + SZ;
    short* vbf = qbf + 2 * SZ;
    float* lpart = ws + SZ + SZ / 2;               // [1.5SZ,+128K floats)
    short* opart = (short*)(ws + 2 * SZ);          // [2SZ,3SZ): 2 x SZ bf16
    float* x1  = ws + 2 * SZ;                      // [2SZ,3SZ): after combine
    short* h   = (short*)(ws + 3 * SZ);            // [3SZ,3.5SZ)
    short* ob  = (short*)(ws + 3 * SZ + SZ / 2);   // [3.5SZ,4SZ)
    short* wqt = (short*)(ws + 4 * SZ);            // [4SZ,4.5SZ): 3xCD*CD + CD*CD
    short* wot = wqt + 3 * CD * CD;
    short* w1t = (short*)(ws + 4 * SZ + SZ / 2);   // [4.5SZ,5SZ)
    short* w2t = (short*)(ws + 5 * SZ);            // [5SZ,5.5SZ)
    short* vtg = (short*)(ws + 5 * SZ + SZ / 2);   // [5.5SZ,6SZ): V^T global
    short* ff1 = (short*)ws;                       // [0,2SZ): reuses dead q/k/v

    // 1) h1 = LN(x)  (bf16)
    ln_kernel<<<BT, 256, 0, stream>>>(x, g1, be1, h);

    // 2) weight transposes (bf16 B^T layouts)
    wqkv_trans<<<dim3(1, 16, 48), 256, 0, stream>>>(Wq, Wk, Wv, wqt);
    transpose_cast<<<dim3(16, 16), 256, 0, stream>>>(Wo, wot, CD, CD);
    transpose_cast<<<dim3(64, 16), 256, 0, stream>>>(W1, w1t, CD, 4 * CD);
    transpose_cast<<<dim3(16, 64), 256, 0, stream>>>(W2, w2t, 4 * CD, CD);

    // 3) merged q|k|v = h1 @ [Wq|Wk|Wv]  (bf16; C^-0.5 folded into q segment)
    gemm_mfma<5, 128><<<dim3(24, 32), 256, 0, stream>>>(h, wqt, nullptr, nullptr, nullptr, qbf, 3 * CD, CD);

    // 4) vtg = V^T per (b,h)
    vtrans<<<dim3(TD / 64, 2 * NH), 256, 0, stream>>>(vbf, vtg);

    // 5) attention split-K -> opart, lpart
    attn_mfma<<<dim3(TD / BQ, NH, BB * 2), 256, 0, stream>>>(qbf, kbf, vtg, opart, lpart);

    // 6) combine -> ob (bf16, concat-head layout)
    attn_combine<<<dim3((int)(SZ / (256 * 8))), 256, 0, stream>>>(opart, lpart, ob);

    // 7) x1 = ob @ Wo + bo + x  (fp32; overwrites opart region after combine)
    gemm_mfma<1, 64><<<dim3(16, 32), 256, 0, stream>>>(ob, wot, bo, x, x1, nullptr, CD, CD);

    // 8) h2 = LN(x1)  (bf16)
    ln_kernel<<<BT, 256, 0, stream>>>(x1, g2, be2, h);

    // 9) ff1 = relu(h2 @ W1 + b1)  (bf16, N=4096)
    gemm_mfma<2, 128><<<dim3(32, 32), 256, 0, stream>>>(h, w1t, b1, nullptr, nullptr, ff1, 4 * CD, CD);

    // 10) out = ff1 @ W2 + b2 + x1  (fp32, K=4096)
    gemm_mfma<1, 64><<<dim3(16, 32), 256, 0, stream>>>(ff1, w2t, b2, x1, out, nullptr, CD, 4 * CD);
}

// Round 9
// 447.163 us; speedup vs baseline: 1.1755x; 1.0012x over previous
//
#include <hip/hip_runtime.h>
#include <hip/hip_bf16.h>

#define BT   4096   // B*T
#define CD   1024   // C
#define TD   2048   // T
#define NH   16     // heads
#define DH   64     // head dim
#define BB   2      // batch

typedef __attribute__((ext_vector_type(8))) short bf16x8;
typedef __attribute__((ext_vector_type(4))) float f32x4;
typedef __attribute__((ext_vector_type(2))) unsigned int u32x2;

__device__ inline short f2bf(float f) {
    union { float fv; unsigned u; } x; x.fv = f;
    unsigned r = x.u + 0x7fffu + ((x.u >> 16) & 1u);
    return (short)(r >> 16);
}
__device__ inline float bf2f(short s) {
    union { unsigned u; float f; } x; x.u = ((unsigned)(unsigned short)s) << 16;
    return x.f;
}
__device__ inline unsigned pk2bf(float a, float b) {
    union { __hip_bfloat162 h; unsigned u; } cv;
    cv.h = __float22bfloat162_rn(float2{a, b});
    return cv.u;
}

__device__ inline void gload_lds16(const short* g, short* lds) {
    __builtin_amdgcn_global_load_lds(
        (const __attribute__((address_space(1))) void*)g,
        (__attribute__((address_space(3))) void*)lds, 16, 0, 0);
}

// ---------------- LayerNorm: one block per row (C=1024), fp32 in, bf16 out ----
__launch_bounds__(256)
__global__ void ln_kernel(const float* __restrict__ x,
                          const float* __restrict__ g,
                          const float* __restrict__ be,
                          short* __restrict__ out) {
    __shared__ float red[2][4];
    const int row = blockIdx.x;
    const float* xr = x + (size_t)row * CD;
    float s = 0.f, ss = 0.f;
    for (int c = threadIdx.x; c < CD; c += 256) {
        float v = xr[c];
        s += v; ss += v * v;
    }
    #pragma unroll
    for (int off = 32; off > 0; off >>= 1) {
        s  += __shfl_down(s,  off, 64);
        ss += __shfl_down(ss, off, 64);
    }
    int wid = threadIdx.x >> 6, lane = threadIdx.x & 63;
    if (lane == 0) { red[0][wid] = s; red[1][wid] = ss; }
    __syncthreads();
    float sum   = red[0][0] + red[0][1] + red[0][2] + red[0][3];
    float sumsq = red[1][0] + red[1][1] + red[1][2] + red[1][3];
    float mu   = sum * (1.f / CD);
    float var  = sumsq * (1.f / CD) - mu * mu;
    float rstd = rsqrtf(var + 1e-5f);
    short* orow = out + (size_t)row * CD;
    for (int c = threadIdx.x; c < CD; c += 256) {
        float v = xr[c];
        orow[c] = f2bf((v - mu) * rstd * g[c] + be[c]);
    }
}

// ------------- Fused weight prep: all 64x64 fp32->bf16 transpose tiles -------
// blocks 0..767: Wq/Wk/Wv (per-head CDxDH slices) -> wqt (3,H,DH,C)
// 768..1023: Wo (CDxCD); 1024..2047: W1 (CDx4CD); 2048..3071: W2 (4CDxCD)
__launch_bounds__(256)
__global__ void prep_weights(const float* __restrict__ Wq, const float* __restrict__ Wk,
                             const float* __restrict__ Wv, const float* __restrict__ Wo,
                             const float* __restrict__ W1, const float* __restrict__ W2,
                             short* __restrict__ wqt, short* __restrict__ wot,
                             short* __restrict__ w1t, short* __restrict__ w2t) {
    __shared__ float tt[64][65];
    const int id = blockIdx.x;
    const float* in; short* out; int R, Cc, r0, c0;
    if (id < 768) {
        int which = id >> 8, rem = id & 255, hh = rem >> 4, ry = rem & 15;
        in  = (which == 0 ? Wq : which == 1 ? Wk : Wv) + (size_t)hh * CD * DH;
        out = wqt + (size_t)which * CD * CD + (size_t)hh * DH * CD;
        R = CD; Cc = DH; r0 = ry * 64; c0 = 0;
    } else if (id < 1024) {
        int t = id - 768;  in = Wo; out = wot; R = CD;     Cc = CD;     r0 = (t >> 4) * 64; c0 = (t & 15) * 64;
    } else if (id < 2048) {
        int t = id - 1024; in = W1; out = w1t; R = CD;     Cc = 4 * CD; r0 = (t >> 6) * 64; c0 = (t & 63) * 64;
    } else {
        int t = id - 2048; in = W2; out = w2t; R = 4 * CD; Cc = CD;     r0 = (t >> 4) * 64; c0 = (t & 15) * 64;
    }
    const int tid = threadIdx.x;
    #pragma unroll
    for (int i = 0; i < 16; ++i) {
        int e = i * 256 + tid;
        tt[e >> 6][e & 63] = in[(size_t)(r0 + (e >> 6)) * Cc + c0 + (e & 63)];
    }
    __syncthreads();
    #pragma unroll
    for (int i = 0; i < 16; ++i) {
        int e = i * 256 + tid;
        out[(size_t)(c0 + (e >> 6)) * R + r0 + (e & 63)] = f2bf(tt[e & 63][e >> 6]);
    }
}

// ------------- V transpose: vbf (BT x C bf16) -> vtg[b][h][d][t] bf16 -------
__launch_bounds__(256)
__global__ void vtrans(const short* __restrict__ vin, short* __restrict__ vout) {
    __shared__ short t[64 * 65];
    const int tid = threadIdx.x;
    const int bh = blockIdx.y;
    const int t0 = blockIdx.x * 64;
    const int b = bh >> 4, h = bh & 15;
    const short* src = vin + (size_t)b * TD * CD + (size_t)h * DH;
    short* dst = vout + (size_t)bh * DH * TD;
    #pragma unroll
    for (int i = 0; i < 16; ++i) {
        int e = i * 256 + tid;
        t[(e >> 6) * 65 + (e & 63)] = src[(size_t)(t0 + (e >> 6)) * CD + (e & 63)];
    }
    __syncthreads();
    #pragma unroll
    for (int i = 0; i < 16; ++i) {
        int e = i * 256 + tid;
        int d = e >> 6, tt = e & 63;
        dst[(size_t)d * TD + t0 + tt] = t[tt * 65 + d];
    }
}

// ---------------- MFMA GEMM: C(128 x TN) = A(M x K) . Bt(N x K)^T, bf16 ------
// MODE 1: + bias + fp32 resid -> fp32 out
// MODE 2: + bias, relu -> bf16 out
// MODE 5: QKV merged: N=3072; seg=col>>10 -> outb + seg*BT*CD; seg0 scaled by
//         C^-0.5 * log2(e)  (attention uses exp2)
template <int MODE, int TN>
__launch_bounds__(256)
__global__ void gemm_mfma(const short* __restrict__ A,
                          const short* __restrict__ Bt,
                          const float* __restrict__ bias,
                          const float* __restrict__ resid,
                          float* __restrict__ outf,
                          short* __restrict__ outb,
                          int N, int K) {
    __shared__ short As[128 * 32];
    __shared__ short Bs[TN * 32];
    const int tid = threadIdx.x;
    const int w = tid >> 6, lane = tid & 63;
    const int quad = lane >> 4, l16 = lane & 15;
    const int wr = w >> 1, wc = w & 1;
    const int m0 = blockIdx.y * 128, n0 = blockIdx.x * TN;
    const int NT = TN / 32;

    f32x4 acc[4][NT] = {};

    for (int k0 = 0; k0 < K; k0 += 32) {
        __syncthreads();
        #pragma unroll
        for (int i = 0; i < 2; ++i) {
            int chunk = i * 256 + tid;
            int row = chunk >> 2, kc = chunk & 3;
            gload_lds16(A + (size_t)(m0 + row) * K + k0 + kc * 8,
                        &As[(i * 256 + w * 64) * 8]);
        }
        #pragma unroll
        for (int i = 0; i < TN / 64; ++i) {
            int chunk = i * 256 + tid;
            int row = chunk >> 2, kc = chunk & 3;
            gload_lds16(Bt + (size_t)(n0 + row) * K + k0 + kc * 8,
                        &Bs[(i * 256 + w * 64) * 8]);
        }
        __syncthreads();

        bf16x8 a[4], b[NT];
        #pragma unroll
        for (int mt = 0; mt < 4; ++mt)
            a[mt] = *(const bf16x8*)&As[(wr * 64 + mt * 16 + l16) * 32 + quad * 8];
        #pragma unroll
        for (int nt = 0; nt < NT; ++nt)
            b[nt] = *(const bf16x8*)&Bs[(wc * (TN / 2) + nt * 16 + l16) * 32 + quad * 8];
        #pragma unroll
        for (int mt = 0; mt < 4; ++mt)
            #pragma unroll
            for (int nt = 0; nt < NT; ++nt)
                acc[mt][nt] = __builtin_amdgcn_mfma_f32_16x16x32_bf16(a[mt], b[nt], acc[mt][nt], 0, 0, 0);
    }

    const float qsc = (MODE == 5 && n0 < CD) ? 0.03125f * 1.44269504f : 1.0f;
    short* ob5 = (MODE == 5) ? outb + (size_t)(n0 >> 10) * BT * CD : nullptr;

    #pragma unroll
    for (int mt = 0; mt < 4; ++mt)
        #pragma unroll
        for (int nt = 0; nt < NT; ++nt)
            #pragma unroll
            for (int reg = 0; reg < 4; ++reg) {
                int row = m0 + wr * 64 + mt * 16 + quad * 4 + reg;
                int col = n0 + wc * (TN / 2) + nt * 16 + l16;
                float v = acc[mt][nt][reg];
                if (MODE == 1) { v += bias[col] + resid[(size_t)row * N + col];
                                 outf[(size_t)row * N + col] = v; }
                if (MODE == 2) { v = fmaxf(v + bias[col], 0.f);
                                 outb[(size_t)row * N + col] = f2bf(v); }
                if (MODE == 5) { ob5[(size_t)row * CD + (col & 1023)] = f2bf(v * qsc); }
            }
}

// ---------------- Flash attention, split-K, MFMA bf16, no-max softmax --------
// Key change vs R8: compute S^T = K.Q^T (swapped mfma operands). C-layout of
// S^T puts q on lanes (col=l16) and keys in regs (row=quad*4+reg), so the
// P -> A-layout LDS transform is 8 packed ds_write_b64 per lane (was 32 b16),
// the l-sum is a per-lane scalar (butterfly only at epilogue), and exp uses
// raw exp2 (log2e folded into q by the QKV GEMM). PV unchanged: A=P rows from
// LDS, B=V^T rows; O C-layout rows = q = quad*4+reg, col = d = l16.
#define BQ   128
#define BK   64
#define STR  76

__launch_bounds__(256)
__global__ void attn_mfma(const short* __restrict__ q,
                          const short* __restrict__ k,
                          const short* __restrict__ vt,
                          short* __restrict__ opart,
                          float* __restrict__ lpart) {
    __shared__ short Ks[BK * STR];
    __shared__ short Vt[DH * STR];
    __shared__ short Pl[BQ * STR];

    const int tid  = threadIdx.x;
    const int w = tid >> 6, lane = tid & 63;
    const int quad = lane >> 4, l16 = lane & 15;
    const int h = blockIdx.y;
    const int b = blockIdx.z >> 1, split = blockIdx.z & 1;
    const int q0 = blockIdx.x * BQ;
    const size_t base  = (size_t)b * TD * CD + (size_t)h * DH;
    const size_t vbase = (size_t)(b * NH + h) * DH * TD;

    // Q frags (N-side of S^T mfma): lane holds Q[q=l16][d=quad*8+j]
    bf16x8 qf[2][2];
    #pragma unroll
    for (int rt = 0; rt < 2; ++rt) {
        const short* qp = q + base + (size_t)(q0 + w * 32 + rt * 16 + l16) * CD;
        qf[rt][0] = *(const bf16x8*)&qp[quad * 8];
        qf[rt][1] = *(const bf16x8*)&qp[32 + quad * 8];
    }

    float l_p[2] = {};   // per-lane: q = q0+w*32+rt*16+l16, keys quad*4+reg
    f32x4 O[2][4] = {};
    short* pw = &Pl[w * 32 * STR];

    const int kbeg = split * (TD / 2), kend = kbeg + TD / 2;
    for (int kt = kbeg; kt < kend; kt += BK) {
        __syncthreads();
        #pragma unroll
        for (int i = 0; i < 2; ++i) {
            int chunk = i * 256 + tid;
            int r8 = chunk >> 3, c8 = (chunk & 7) * 8;
            *(bf16x8*)&Ks[r8 * STR + c8] =
                *(const bf16x8*)&k[base + (size_t)(kt + r8) * CD + c8];
            *(bf16x8*)&Vt[r8 * STR + c8] =
                *(const bf16x8*)&vt[vbase + (size_t)r8 * TD + kt + c8];
        }
        __syncthreads();

        // S^T = K.Q^T  (C-layout: row key = quad*4+reg, col q = l16)
        f32x4 S[2][4];
        #pragma unroll
        for (int ct = 0; ct < 4; ++ct) {
            bf16x8 kb0 = *(const bf16x8*)&Ks[(ct * 16 + l16) * STR + quad * 8];
            bf16x8 kb1 = *(const bf16x8*)&Ks[(ct * 16 + l16) * STR + 32 + quad * 8];
            #pragma unroll
            for (int rt = 0; rt < 2; ++rt) {
                f32x4 acc = (f32x4){0.f, 0.f, 0.f, 0.f};
                acc = __builtin_amdgcn_mfma_f32_16x16x32_bf16(kb0, qf[rt][0], acc, 0, 0, 0);
                acc = __builtin_amdgcn_mfma_f32_16x16x32_bf16(kb1, qf[rt][1], acc, 0, 0, 0);
                S[rt][ct] = acc;
            }
        }

        // P = exp2(S^T); l partial per lane; packed b64 write to A-layout rows
        #pragma unroll
        for (int rt = 0; rt < 2; ++rt)
            #pragma unroll
            for (int ct = 0; ct < 4; ++ct) {
                float p0 = exp2f(S[rt][ct][0]), p1 = exp2f(S[rt][ct][1]);
                float p2 = exp2f(S[rt][ct][2]), p3 = exp2f(S[rt][ct][3]);
                l_p[rt] += (p0 + p1) + (p2 + p3);
                u32x2 pkd = (u32x2){pk2bf(p0, p1), pk2bf(p2, p3)};
                *(u32x2*)&pw[(rt * 16 + l16) * STR + ct * 16 + quad * 4] = pkd;
            }
        // same-wave LDS write->read: lgkmcnt-ordered, no barrier needed

        bf16x8 pf[2][2];
        #pragma unroll
        for (int rt = 0; rt < 2; ++rt) {
            pf[rt][0] = *(const bf16x8*)&pw[(rt * 16 + l16) * STR + quad * 8];
            pf[rt][1] = *(const bf16x8*)&pw[(rt * 16 + l16) * STR + 32 + quad * 8];
        }
        #pragma unroll
        for (int dt = 0; dt < 4; ++dt) {
            bf16x8 vf0 = *(const bf16x8*)&Vt[(dt * 16 + l16) * STR + quad * 8];
            bf16x8 vf1 = *(const bf16x8*)&Vt[(dt * 16 + l16) * STR + 32 + quad * 8];
            #pragma unroll
            for (int rt = 0; rt < 2; ++rt) {
                f32x4 acc = O[rt][dt];
                acc = __builtin_amdgcn_mfma_f32_16x16x32_bf16(pf[rt][0], vf0, acc, 0, 0, 0);
                acc = __builtin_amdgcn_mfma_f32_16x16x32_bf16(pf[rt][1], vf1, acc, 0, 0, 0);
                O[rt][dt] = acc;
            }
        }
    }

    // epilogue: unnormalized O (bf16) + l (fp32) per split
    short* osp = opart + (size_t)split * BT * CD;
    float* lsp = lpart + (size_t)split * BB * NH * TD + (size_t)(b * NH + h) * TD;
    #pragma unroll
    for (int rt = 0; rt < 2; ++rt) {
        float l = l_p[rt];
        l += __shfl_xor(l, 16, 64);
        l += __shfl_xor(l, 32, 64);
        if (lane < 16) lsp[q0 + w * 32 + rt * 16 + lane] = l;
        #pragma unroll
        for (int reg = 0; reg < 4; ++reg) {
            int row = q0 + w * 32 + rt * 16 + quad * 4 + reg;
            short* op = osp + base + (size_t)row * CD;
            #pragma unroll
            for (int dt = 0; dt < 4; ++dt)
                op[dt * 16 + l16] = f2bf(O[rt][dt][reg]);
        }
    }
}

// ---------------- Combine split-K partials: ob = (O0+O1)/(l0+l1), bf16 -------
__launch_bounds__(256)
__global__ void attn_combine(const short* __restrict__ opart,
                             const float* __restrict__ lpart,
                             short* __restrict__ ob) {
    const size_t idx = ((size_t)blockIdx.x * 256 + threadIdx.x) * 8;
    const int row = (int)(idx >> 10);        // / CD
    const int col = (int)(idx & 1023);
    const int b = row >> 11, qq = row & (TD - 1), hh = col >> 6;
    const size_t lbase = (size_t)(b * NH + hh) * TD + qq;
    const float l0 = lpart[lbase];
    const float l1 = lpart[(size_t)BB * NH * TD + lbase];
    const float inv = 1.f / (l0 + l1);
    bf16x8 a = *(const bf16x8*)&opart[idx];
    bf16x8 c = *(const bf16x8*)&opart[(size_t)BT * CD + idx];
    bf16x8 r;
    #pragma unroll
    for (int j = 0; j < 8; ++j)
        r[j] = f2bf((bf2f(a[j]) + bf2f(c[j])) * inv);
    *(bf16x8*)&ob[idx] = r;
}

extern "C" void kernel_launch(void* const* d_in, const int* in_sizes, int n_in,
                              void* d_out, int out_size, void* d_ws, size_t ws_size,
                              hipStream_t stream) {
    const float* x   = (const float*)d_in[0];
    const float* Wq  = (const float*)d_in[1];
    const float* Wk  = (const float*)d_in[2];
    const float* Wv  = (const float*)d_in[3];
    const float* Wo  = (const float*)d_in[4];
    const float* bo  = (const float*)d_in[5];
    const float* W1  = (const float*)d_in[6];
    const float* b1  = (const float*)d_in[7];
    const float* W2  = (const float*)d_in[8];
    const float* b2  = (const float*)d_in[9];
    const float* g1  = (const float*)d_in[10];
    const float* be1 = (const float*)d_in[11];
    const float* g2  = (const float*)d_in[12];
    const float* be2 = (const float*)d_in[13];
    float* out = (float*)d_out;

    const size_t SZ = (size_t)BT * CD;  // 4M elements
    float* ws  = (float*)d_ws;
    short* qbf = (short*)ws;                       // [0,1.5SZ): q|k|v bf16
    short* kbf = qbf + SZ;
    short* vbf = qbf + 2 * SZ;
    float* lpart = ws + SZ + SZ / 2;               // [1.5SZ,+128K floats)
    short* opart = (short*)(ws + 2 * SZ);          // [2SZ,3SZ): 2 x SZ bf16
    float* x1  = ws + 2 * SZ;                      // [2SZ,3SZ): after combine
    short* h   = (short*)(ws + 3 * SZ);            // [3SZ,3.5SZ)
    short* ob  = (short*)(ws + 3 * SZ + SZ / 2);   // [3.5SZ,4SZ)
    short* wqt = (short*)(ws + 4 * SZ);            // [4SZ,4.5SZ): 3xCD*CD + CD*CD
    short* wot = wqt + 3 * CD * CD;
    short* w1t = (short*)(ws + 4 * SZ + SZ / 2);   // [4.5SZ,5SZ)
    short* w2t = (short*)(ws + 5 * SZ);            // [5SZ,5.5SZ)
    short* vtg = (short*)(ws + 5 * SZ + SZ / 2);   // [5.5SZ,6SZ): V^T global
    short* ff1 = (short*)ws;                       // [0,2SZ): reuses dead q/k/v

    // 1) h1 = LN(x)  (bf16)
    ln_kernel<<<BT, 256, 0, stream>>>(x, g1, be1, h);

    // 2) all weight transposes fused (bf16 B^T layouts)
    prep_weights<<<3072, 256, 0, stream>>>(Wq, Wk, Wv, Wo, W1, W2, wqt, wot, w1t, w2t);

    // 3) merged q|k|v = h1 @ [Wq|Wk|Wv]  (bf16; C^-0.5*log2e folded into q)
    gemm_mfma<5, 128><<<dim3(24, 32), 256, 0, stream>>>(h, wqt, nullptr, nullptr, nullptr, qbf, 3 * CD, CD);

    // 4) vtg = V^T per (b,h)
    vtrans<<<dim3(TD / 64, 2 * NH), 256, 0, stream>>>(vbf, vtg);

    // 5) attention split-K -> opart, lpart
    attn_mfma<<<dim3(TD / BQ, NH, BB * 2), 256, 0, stream>>>(qbf, kbf, vtg, opart, lpart);

    // 6) combine -> ob (bf16, concat-head layout)
    attn_combine<<<dim3((int)(SZ / (256 * 8))), 256, 0, stream>>>(opart, lpart, ob);

    // 7) x1 = ob @ Wo + bo + x  (fp32; overwrites opart region after combine)
    gemm_mfma<1, 64><<<dim3(16, 32), 256, 0, stream>>>(ob, wot, bo, x, x1, nullptr, CD, CD);

    // 8) h2 = LN(x1)  (bf16)
    ln_kernel<<<BT, 256, 0, stream>>>(x1, g2, be2, h);

    // 9) ff1 = relu(h2 @ W1 + b1)  (bf16, N=4096)
    gemm_mfma<2, 128><<<dim3(32, 32), 256, 0, stream>>>(h, w1t, b1, nullptr, nullptr, ff1, 4 * CD, CD);

    // 10) out = ff1 @ W2 + b2 + x1  (fp32, K=4096)
    gemm_mfma<1, 64><<<dim3(16, 32), 256, 0, stream>>>(ff1, w2t, b2, x1, out, nullptr, CD, 4 * CD);
}